// Round 1
// baseline (3036.066 us; speedup 1.0000x reference)
//
#include <hip/hip_runtime.h>
#include <cstddef>
#include <cstdint>

// Problem constants (from reference)
#define TSTEPS 256
#define HDIM 50      // real hidden units
#define BTOT 4096
#define MB 16        // batch elements per block
#define NTHR 256     // threads per block (4 waves)

// Inter-layer h timeseries buffer: (B, T, H) f32 = 209.7 MB.
// Static __device__ (ws_size unknown). Fully rewritten by layer 0 each call
// before any read -> deterministic across graph replays.
__device__ float g_hbuf[(size_t)BTOT * TSTEPS * HDIM];

__device__ __forceinline__ float fast_sigmoid(float x) {
    // 1 / (1 + e^-x) ; e^-x = 2^(-x*log2e). Saturates cleanly (no NaN).
    float e = __builtin_amdgcn_exp2f(-1.4426950408889634f * x);
    return __builtin_amdgcn_rcpf(1.0f + e);
}
__device__ __forceinline__ float fast_tanh(float x) {
    // tanh = 1 - 2/(e^{2x}+1); x->+inf: e=inf -> 1; x->-inf: e=0 -> -1. No NaN.
    float e = __builtin_amdgcn_exp2f(2.8853900817779268f * x);
    return 1.0f - 2.0f * __builtin_amdgcn_rcpf(1.0f + e);
}

// One LSTM layer over all T steps, 16 batch elements per block.
// Thread (u = tid&63, bg = tid>>6): unit u (padded to 64), 4 batches bg*4..bg*4+3.
// acc[4 gate types][4 batches] register tile: each weight ds_read_b128 feeds 16 FMAs;
// activation reads are wave-uniform broadcasts.
// LDS: Wl[4][64][JP] (weights, rows stride JP floats: JP/4 odd -> conflict-free b128)
//      Ab[2][MB][JP]  (activations [x_t | h_t], double-buffered, 1 barrier/step)
template<int D, int JP, bool XIN_HBUF, bool WRITE_H, bool LAST>
__global__ __launch_bounds__(NTHR) void lstm_layer(
    const float* xin_p,
    const float* __restrict__ w_ih, const float* __restrict__ w_hh,
    const float* __restrict__ b_ih, const float* __restrict__ b_hh,
    const float* __restrict__ w_fc, const float* __restrict__ b_fc,
    float* __restrict__ out)
{
    extern __shared__ __align__(16) float smem[];
    float* Wl = smem;                       // [4][64][JP]
    float* Ab = smem + 4 * 64 * JP;         // [2][MB][JP]

    const int tid = threadIdx.x;
    const int u   = tid & 63;
    const int bg  = tid >> 6;               // 0..3
    const int b0  = blockIdx.x * MB;

    const float* xin = XIN_HBUF ? (const float*)g_hbuf : xin_p;

    // ---- prologue: zero LDS, stage weights, load x_0 ----
    for (int i = tid; i < 4 * 64 * JP; i += NTHR) Wl[i] = 0.0f;
    for (int i = tid; i < 2 * MB * JP; i += NTHR) Ab[i] = 0.0f;
    __syncthreads();

    for (int i = tid; i < 200 * (D + HDIM); i += NTHR) {
        int gi = i / (D + HDIM);
        int j  = i % (D + HDIM);
        int gt = gi / HDIM;
        int n  = gi % HDIM;
        float v = (j < D) ? w_ih[gi * D + j] : w_hh[gi * HDIM + (j - D)];
        Wl[(gt * 64 + n) * JP + j] = v;
    }
    for (int i = tid; i < MB * D; i += NTHR) {
        int b = i / D, j = i % D;
        Ab[b * JP + j] = xin[((size_t)(b0 + b) * TSTEPS + 0) * D + j];
    }

    float bias_s[4];
    #pragma unroll
    for (int g = 0; g < 4; ++g)
        bias_s[g] = (u < HDIM) ? (b_ih[g * HDIM + u] + b_hh[g * HDIM + u]) : 0.0f;

    float cst[4] = {0.0f, 0.0f, 0.0f, 0.0f};
    __syncthreads();

    constexpr int XR = (MB * D + NTHR - 1) / NTHR;  // prefetch regs per thread

    // ---- main scan ----
    for (int t = 0; t < TSTEPS; ++t) {
        const int cur = t & 1, nxt = cur ^ 1;

        // prefetch next step's input (overlaps with gate compute)
        float xr[XR];
        if (t + 1 < TSTEPS) {
            #pragma unroll
            for (int k = 0; k < XR; ++k) {
                int idx = tid + k * NTHR;
                if (idx < MB * D) {
                    int b = idx / D, j = idx % D;
                    xr[k] = xin[((size_t)(b0 + b) * TSTEPS + (t + 1)) * D + j];
                }
            }
        }

        // gates: acc[gate][batch] = bias + sum_j W[g][u][j] * a[b][j]
        float acc[4][4];
        #pragma unroll
        for (int g = 0; g < 4; ++g)
            #pragma unroll
            for (int b = 0; b < 4; ++b) acc[g][b] = bias_s[g];

        const float* Ar = Ab + (cur * MB + bg * 4) * JP;
        #pragma unroll 5
        for (int jb = 0; jb < JP / 4; ++jb) {
            float4 wv[4], av[4];
            #pragma unroll
            for (int g = 0; g < 4; ++g)
                wv[g] = *(const float4*)(Wl + (g * 64 + u) * JP + jb * 4);
            #pragma unroll
            for (int b = 0; b < 4; ++b)
                av[b] = *(const float4*)(Ar + b * JP + jb * 4);
            #pragma unroll
            for (int g = 0; g < 4; ++g)
                #pragma unroll
                for (int b = 0; b < 4; ++b) {
                    acc[g][b] = fmaf(wv[g].x, av[b].x, acc[g][b]);
                    acc[g][b] = fmaf(wv[g].y, av[b].y, acc[g][b]);
                    acc[g][b] = fmaf(wv[g].z, av[b].z, acc[g][b]);
                    acc[g][b] = fmaf(wv[g].w, av[b].w, acc[g][b]);
                }
        }

        // nonlinearity + state update (all in registers)
        float hv[4];
        #pragma unroll
        for (int b = 0; b < 4; ++b) {
            float ig = fast_sigmoid(acc[0][b]);
            float fg = fast_sigmoid(acc[1][b]);
            float gg = fast_tanh(acc[2][b]);
            float og = fast_sigmoid(acc[3][b]);
            float c  = fmaf(fg, cst[b], ig * gg);
            cst[b] = c;
            hv[b]  = og * fast_tanh(c);
        }

        // write h_t into next activation buffer (+ global for next layer)
        if (u < HDIM) {
            #pragma unroll
            for (int b = 0; b < 4; ++b)
                Ab[(nxt * MB + bg * 4 + b) * JP + D + u] = hv[b];
            if (WRITE_H) {
                #pragma unroll
                for (int b = 0; b < 4; ++b)
                    g_hbuf[((size_t)(b0 + bg * 4 + b) * TSTEPS + t) * HDIM + u] = hv[b];
            }
        }
        // commit prefetched x_{t+1}
        if (t + 1 < TSTEPS) {
            #pragma unroll
            for (int k = 0; k < XR; ++k) {
                int idx = tid + k * NTHR;
                if (idx < MB * D) {
                    int b = idx / D, j = idx % D;
                    Ab[(nxt * MB + b) * JP + j] = xr[k];
                }
            }
        }
        __syncthreads();
    }

    if (LAST) {
        // h_255 sits in buffer (255+1)&1 == 0, cols [D, D+50)
        if (tid < MB * 6) {
            int b = tid / 6, o = tid % 6;
            float a = b_fc[o];
            for (int n = 0; n < HDIM; ++n)
                a = fmaf(w_fc[o * HDIM + n], Ab[b * JP + D + n], a);
            out[(size_t)(b0 + b) * 6 + o] = a;
        }
    }
}

extern "C" void kernel_launch(void* const* d_in, const int* in_sizes, int n_in,
                              void* d_out, int out_size, void* d_ws, size_t ws_size,
                              hipStream_t stream) {
    (void)in_sizes; (void)n_in; (void)d_ws; (void)ws_size; (void)out_size;

    const float* x     = (const float*)d_in[0];
    const float* w_ih0 = (const float*)d_in[1];
    const float* w_hh0 = (const float*)d_in[2];
    const float* b_ih0 = (const float*)d_in[3];
    const float* b_hh0 = (const float*)d_in[4];
    const float* w_ih1 = (const float*)d_in[5];
    const float* w_hh1 = (const float*)d_in[6];
    const float* b_ih1 = (const float*)d_in[7];
    const float* b_hh1 = (const float*)d_in[8];
    const float* w_ih2 = (const float*)d_in[9];
    const float* w_hh2 = (const float*)d_in[10];
    const float* b_ih2 = (const float*)d_in[11];
    const float* b_hh2 = (const float*)d_in[12];
    const float* w_fc  = (const float*)d_in[13];
    const float* b_fc  = (const float*)d_in[14];
    float* out = (float*)d_out;

    auto k0 = lstm_layer<8,  60,  false, true,  false>;
    auto k1 = lstm_layer<50, 100, true,  true,  false>;
    auto k2 = lstm_layer<50, 100, true,  false, true>;

    // Dynamic LDS > 64KB needs opt-in. L0 request padded to 84000 so two L0
    // blocks never co-schedule on one CU (keeps 1 block/CU everywhere).
    const int lds0 = 84000;
    const int lds12 = (4 * 64 * 100 + 2 * MB * 100) * 4;  // 115200
    hipFuncSetAttribute((const void*)k0, hipFuncAttributeMaxDynamicSharedMemorySize, lds0);
    hipFuncSetAttribute((const void*)k1, hipFuncAttributeMaxDynamicSharedMemorySize, lds12);
    hipFuncSetAttribute((const void*)k2, hipFuncAttributeMaxDynamicSharedMemorySize, lds12);

    dim3 grid(BTOT / MB), block(NTHR);
    k0<<<grid, block, lds0,  stream>>>(x,       w_ih0, w_hh0, b_ih0, b_hh0, nullptr, nullptr, out);
    k1<<<grid, block, lds12, stream>>>(nullptr, w_ih1, w_hh1, b_ih1, b_hh1, nullptr, nullptr, out);
    k2<<<grid, block, lds12, stream>>>(nullptr, w_ih2, w_hh2, b_ih2, b_hh2, w_fc,    b_fc,    out);
}